// Round 11
// baseline (477.347 us; speedup 1.0000x reference)
//
#include <hip/hip_runtime.h>
#include <hip/hip_bf16.h>

#define IN_CH   128
#define HID     8
#define HEADS   8
#define C1      64      // HEADS*HID
#define OUT_CH  40
#define NEG     0.2f
#define NPART   8       // dst-space partitions, mapped to XCDs via blockIdx&7

typedef __attribute__((ext_vector_type(8))) short  short8;   // 8 bf16 (4 VGPRs)
typedef __attribute__((ext_vector_type(4))) float  f32x4;    // 4 fp32 acc

__device__ __forceinline__ float b2f(unsigned short u) {
    return __uint_as_float(((unsigned int)u) << 16);
}
__device__ __forceinline__ float blo(unsigned int p) { return __uint_as_float(p << 16); }
__device__ __forceinline__ float bhi(unsigned int p) { return __uint_as_float(p & 0xffff0000u); }
__device__ __forceinline__ unsigned short f2b(float f) {
    unsigned int u = __float_as_uint(f);
    unsigned int r = (u + 0x7fffu + ((u >> 16) & 1u)) >> 16;
    return (unsigned short)r;
}
__device__ __forceinline__ float lrelu(float v) { return v > 0.f ? v : NEG * v; }

// Param-block offsets (floats) inside canonical fp32 param buffer
#define P_W1    0
#define P_AS1   8192
#define P_AD1   8256
#define P_B1    8320
#define P_W2    8384
#define P_AS2   10944
#define P_AD2   10984
#define P_B2    11024
#define P_TOT   11064

// ---- kA_fused: dtype flag + param conversion (blocks 0..7) + partitioned
// histogram with int4 edge reads. 1024 blocks = 8 partitions x 128.
__global__ __launch_bounds__(256) void kA_fused(
        const unsigned int* __restrict__ x32,
        const void* W1, const void* as1p, const void* ad1p, const void* b1,
        const void* W2, const void* as2p, const void* ad2p, const void* b2,
        const int* __restrict__ dst, int* __restrict__ deg,
        int* __restrict__ flag, float* __restrict__ pf,
        unsigned short* __restrict__ w1bf,
        int e_all, int n_nodes) {
    int t = threadIdx.x;
    __shared__ int sflag;
    if (t < 64) {
        unsigned int lo = x32[t] & 0xffffu;
        int ex = (int)((lo >> 7) & 0xff);
        bool sane = (ex >= 112 && ex <= 143);
        unsigned long long m = __ballot(sane);
        if (t == 0) {
            int isbf = (__popcll(m) >= 32) ? 1 : 0;
            sflag = isbf;
            if (blockIdx.x == 0) *flag = isbf;
        }
    }
    __syncthreads();
    const int isbf = sflag;

    if (blockIdx.x < 8) {
        int g = blockIdx.x * 256 + t;     // 2048 threads over param arrays
#define CONV(dstoff, srcp, cnt)                                         \
        if (isbf) {                                                     \
            const unsigned short* sp = (const unsigned short*)(srcp);   \
            for (int i = g; i < (cnt); i += 2048) pf[(dstoff) + i] = b2f(sp[i]); \
        } else {                                                        \
            const float* sp = (const float*)(srcp);                     \
            for (int i = g; i < (cnt); i += 2048) pf[(dstoff) + i] = sp[i]; \
        }
        CONV(P_W1,  W1, 8192)
        CONV(P_AS1, as1p, 64)
        CONV(P_AD1, ad1p, 64)
        CONV(P_B1,  b1, 64)
        CONV(P_W2,  W2, 2560)
        CONV(P_AS2, as2p, 40)
        CONV(P_AD2, ad2p, 40)
        CONV(P_B2,  b2, 40)
#undef CONV
        if (isbf) {
            const unsigned short* sp = (const unsigned short*)W1;
            for (int i = g; i < 8192; i += 2048) w1bf[i] = sp[i];
        } else {
            const float* sp = (const float*)W1;
            for (int i = g; i < 8192; i += 2048) w1bf[i] = f2b(sp[i]);
        }
    }

    // partitioned histogram, int4 reads
    int part = blockIdx.x & (NPART - 1);
    int nm   = gridDim.x >> 3;
    int mblk = blockIdx.x >> 3;
    int lo = (int)((long long)part * n_nodes / NPART);
    int hi = (int)((long long)(part + 1) * n_nodes / NPART);
    const int4* dst4 = (const int4*)dst;
    int e4n = e_all >> 2;
    for (int i = mblk * 256 + t; i < e4n; i += nm * 256) {
        int4 d4 = dst4[i];
        if (d4.x >= lo && d4.x < hi) atomicAdd(&deg[d4.x], 1);
        if (d4.y >= lo && d4.y < hi) atomicAdd(&deg[d4.y], 1);
        if (d4.z >= lo && d4.z < hi) atomicAdd(&deg[d4.z], 1);
        if (d4.w >= lo && d4.w < hi) atomicAdd(&deg[d4.w], 1);
    }
    for (int e = (e4n << 2) + mblk * 256 + t; e < e_all; e += nm * 256) {
        int d = dst[e];
        if (d >= lo && d < hi) atomicAdd(&deg[d], 1);
    }
}

__global__ __launch_bounds__(256) void kB1_scan(
        const int* __restrict__ deg, int* __restrict__ offs,
        int* __restrict__ bsum, int n) {
    __shared__ int sd[256];
    int t = threadIdx.x;
    int i = blockIdx.x * 256 + t;
    int v = (i < n) ? deg[i] : 0;
    sd[t] = v;
    __syncthreads();
    for (int off = 1; off < 256; off <<= 1) {
        int u = (t >= off) ? sd[t - off] : 0;
        __syncthreads();
        sd[t] += u;
        __syncthreads();
    }
    if (i < n) offs[i] = sd[t] - v;
    if (t == 255) bsum[blockIdx.x] = sd[255];
}

__global__ __launch_bounds__(512) void kB2_scanb(
        const int* __restrict__ bsum, int* __restrict__ bsumx, int nb) {
    __shared__ int sd[512];
    int t = threadIdx.x;
    int v = (t < nb) ? bsum[t] : 0;
    sd[t] = v;
    __syncthreads();
    for (int off = 1; off < 512; off <<= 1) {
        int u = (t >= off) ? sd[t - off] : 0;
        __syncthreads();
        sd[t] += u;
        __syncthreads();
    }
    if (t < nb) bsumx[t] = sd[t] - v;
}

__global__ __launch_bounds__(256) void kB3_fix(
        int* __restrict__ offs, const int* __restrict__ bsumx,
        int* __restrict__ cursor, int n) {
    int i = blockIdx.x * 256 + threadIdx.x;
    if (i >= n) return;
    int o = offs[i] + bsumx[blockIdx.x];
    offs[i] = o;
    cursor[i] = o;
}

__global__ __launch_bounds__(256) void kC_scatter(
        const int* __restrict__ src, const int* __restrict__ dst,
        int* __restrict__ cursor, int* __restrict__ csr_src,
        int e_all, int n_nodes) {
    int part = blockIdx.x & (NPART - 1);
    int nm   = gridDim.x >> 3;
    int mblk = blockIdx.x >> 3;
    int lo = (int)((long long)part * n_nodes / NPART);
    int hi = (int)((long long)(part + 1) * n_nodes / NPART);
    const int4* dst4 = (const int4*)dst;
    int e4n = e_all >> 2;
    for (int i = mblk * 256 + threadIdx.x; i < e4n; i += nm * 256) {
        int4 d4 = dst4[i];
        int eb = i << 2;
        if (d4.x >= lo && d4.x < hi) { int p = atomicAdd(&cursor[d4.x], 1); csr_src[p] = src[eb]; }
        if (d4.y >= lo && d4.y < hi) { int p = atomicAdd(&cursor[d4.y], 1); csr_src[p] = src[eb + 1]; }
        if (d4.z >= lo && d4.z < hi) { int p = atomicAdd(&cursor[d4.z], 1); csr_src[p] = src[eb + 2]; }
        if (d4.w >= lo && d4.w < hi) { int p = atomicAdd(&cursor[d4.w], 1); csr_src[p] = src[eb + 3]; }
    }
    for (int e = (e4n << 2) + mblk * 256 + threadIdx.x; e < e_all; e += nm * 256) {
        int d = dst[e];
        if (d >= lo && d < hi) { int p = atomicAdd(&cursor[d], 1); csr_src[p] = src[e]; }
    }
}

// ---- Layer 1 via MFMA: h1 = x @ W1^T, logits as1/ad1 --------------------
__global__ __launch_bounds__(256) void k1_mfma(
        const void* __restrict__ x, const unsigned short* __restrict__ w1bf,
        const float* __restrict__ pf, const int* __restrict__ flagp,
        unsigned short* __restrict__ h1b, float* __restrict__ as1, float* __restrict__ ad1,
        int n_nodes) {
    int tid = threadIdx.x;
    int wv = tid >> 6, L = tid & 63;
    int m = L & 15, q = L >> 4;
    int base = blockIdx.x * 64 + wv * 16;
    if (base >= n_nodes) return;
    const int isbf = *flagp;

    short8 bfr[4][4];
#pragma unroll
    for (int t = 0; t < 4; ++t)
#pragma unroll
        for (int kb = 0; kb < 4; ++kb)
            bfr[t][kb] = *(const short8*)(w1bf + (size_t)(t * 16 + m) * IN_CH + kb * 32 + q * 8);

    int row = base + m;
    if (row >= n_nodes) row = n_nodes - 1;   // tail clamp (loads only)
    short8 af[4];
    if (isbf) {
        const unsigned short* xr = (const unsigned short*)x + (size_t)row * IN_CH + q * 8;
#pragma unroll
        for (int kb = 0; kb < 4; ++kb) af[kb] = *(const short8*)(xr + kb * 32);
    } else {
        const float* xr = (const float*)x + (size_t)row * IN_CH + q * 8;
#pragma unroll
        for (int kb = 0; kb < 4; ++kb) {
            short8 a;
#pragma unroll
            for (int j = 0; j < 8; ++j) a[j] = (short)f2b(xr[kb * 32 + j]);
            af[kb] = a;
        }
    }

    f32x4 acc[4];
#pragma unroll
    for (int t = 0; t < 4; ++t) acc[t] = (f32x4){0.f, 0.f, 0.f, 0.f};
#pragma unroll
    for (int t = 0; t < 4; ++t)
#pragma unroll
        for (int kb = 0; kb < 4; ++kb)
            acc[t] = __builtin_amdgcn_mfma_f32_16x16x32_bf16(af[kb], bfr[t][kb], acc[t], 0, 0, 0);

#pragma unroll
    for (int t = 0; t < 4; ++t) {
#pragma unroll
        for (int r = 0; r < 4; ++r) {
            int node = base + q * 4 + r;
            bool ok = (node < n_nodes);
            float val = acc[t][r];
            int ch = t * 16 + m;
            if (ok) h1b[(size_t)node * C1 + ch] = f2b(val);
            float ps = val * pf[P_AS1 + ch];
            float pd = val * pf[P_AD1 + ch];
            ps += __shfl_xor(ps, 1, 64); ps += __shfl_xor(ps, 2, 64); ps += __shfl_xor(ps, 4, 64);
            pd += __shfl_xor(pd, 1, 64); pd += __shfl_xor(pd, 2, 64); pd += __shfl_xor(pd, 4, 64);
            if (ok && (L & 7) == 0) {
                int head = 2 * t + ((m >> 3) & 1);
                as1[(size_t)node * HEADS + head] = ps;
                ad1[(size_t)node * HEADS + head] = pd;
            }
        }
    }
}

// ---- Fused layer-1 agg + ELU + layer-2 GEMM: wave loops over 8 nodes ----
// Block = 4 waves x 8 nodes = 32 dst/block; W2 staged ONCE per block (k4's
// amortization). Agg two-phase; x2 row stays in LDS wave-slice; no barriers
// inside the node loop.
__global__ __launch_bounds__(256) void k34_fused(
        const int* __restrict__ offs, const int* __restrict__ deg,
        const int* __restrict__ csr_src,
        const float* __restrict__ as1, const float* __restrict__ ad1,
        const unsigned short* __restrict__ h1b, const float* __restrict__ pf,
        unsigned short* __restrict__ h2b, float* __restrict__ as2v, float* __restrict__ ad2v,
        int n_nodes) {
    int tid = threadIdx.x;
    int w = tid >> 6, t = tid & 63;
    __shared__ float wTf[4096];          // W2 rotated, 16 groups x 64 slots x 4
    __shared__ float xsf[4 * C1];
    for (int e = tid; e < 2560; e += 256) {
        int row = e >> 6, k = e & 63;
        int g = k >> 2, j = k & 3;
        wTf[(g * 64 + ((row + g) & 63)) * 4 + j] = pf[P_W2 + e];
    }
    __syncthreads();
    const float4* wT4 = (const float4*)wTf;

    int head = t >> 3;
    int j8 = t >> 3, h8 = t & 7;
    int nodebase = blockIdx.x * 32 + w * 8;

    for (int i = 0; i < 8; ++i) {
        int d = nodebase + i;                 // wave-uniform
        if (d >= n_nodes) break;

        // ---- layer-1 aggregation (two-phase) ----
        float adv1 = ad1[(size_t)d * HEADS + h8];
        int start = offs[d];
        int dg = deg[d];
        float acc = 0.f, den = 0.f;
        int nfull = dg & ~7;
        int base = 0;
        for (; base < nfull; base += 8) {
            int s = csr_src[start + base + j8];
            float v = as1[(size_t)s * HEADS + h8] + adv1;
            float wgt = __expf(lrelu(v));
#pragma unroll
            for (int jj = 0; jj < 8; ++jj) {
                int sj   = __shfl(s, jj * 8, 64);
                float wj = __shfl(wgt, jj * 8 + head, 64);
                float hv = b2f(h1b[(size_t)sj * C1 + t]);
                den += wj;
                acc += wj * hv;
            }
        }
        int rem = dg - nfull;
        if (rem) {
            int s = 0; float wgt = 0.f;
            if (j8 < rem) {
                s = csr_src[start + base + j8];
                float v = as1[(size_t)s * HEADS + h8] + adv1;
                wgt = __expf(lrelu(v));
            }
            for (int jj = 0; jj < rem; ++jj) {
                int sj   = __shfl(s, jj * 8, 64);
                float wj = __shfl(wgt, jj * 8 + head, 64);
                float hv = b2f(h1b[(size_t)sj * C1 + t]);
                den += wj;
                acc += wj * hv;
            }
        }
        float o = acc / den + pf[P_B1 + t];
        o = o > 0.f ? o : (__expf(o) - 1.f);     // ELU
        xsf[w * C1 + t] = o;                     // per-wave slice, wave-sync RAW

        // ---- layer-2 GEMM (40 ch) + logits ----
        float hs = 0.f, hd = 0.f;
        if (t < OUT_CH) {
            const float4* xv = (const float4*)(xsf + w * C1);
            float a2 = 0.f;
#pragma unroll
            for (int g = 0; g < 16; ++g) {
                float4 wv = wT4[g * 64 + ((t + g) & 63)];
                float4 x4 = xv[g];
                a2 += x4.x * wv.x + x4.y * wv.y + x4.z * wv.z + x4.w * wv.w;
            }
            h2b[(size_t)d * OUT_CH + t] = f2b(a2);
            hs = a2 * pf[P_AS2 + t];
            hd = a2 * pf[P_AD2 + t];
        }
        for (int off = 1; off < 64; off <<= 1) {
            hs += __shfl_xor(hs, off, 64);
            hd += __shfl_xor(hd, off, 64);
        }
        if (t == 0) { as2v[d] = hs; ad2v[d] = hd; }
    }
}

// ---- Fused layer-2 aggregation: two-phase (16 weights in parallel) ------
__global__ __launch_bounds__(256) void k6_fused2(
        const int* __restrict__ offs, const int* __restrict__ deg,
        const int* __restrict__ csr_src,
        const float* __restrict__ as2, const float* __restrict__ ad2,
        const unsigned short* __restrict__ h2b, const float* __restrict__ pf,
        const int* __restrict__ flagp, void* __restrict__ outp, int n_nodes) {
    int d = blockIdx.x * 4 + (threadIdx.x >> 6);
    if (d >= n_nodes) return;
    int t = threadIdx.x & 63;
    float adv = ad2[d];
    int start = offs[d];
    int dg = deg[d];
    bool act = (t < OUT_CH);
    int tc = act ? t : 0;
    float acc = 0.f, den = 0.f;
    int nfull = dg & ~15;
    int base = 0;
    for (; base < nfull; base += 16) {
        int s = 0; float w = 0.f;
        if (t < 16) {
            s = csr_src[start + base + t];
            w = __expf(lrelu(as2[s] + adv));
        }
#pragma unroll
        for (int jj = 0; jj < 16; ++jj) {
            int sj   = __shfl(s, jj, 64);
            float wj = __shfl(w, jj, 64);
            float hv = b2f(h2b[(size_t)sj * OUT_CH + tc]);
            den += wj;
            acc += wj * hv;
        }
    }
    int rem = dg - nfull;
    if (rem) {
        int s = 0; float w = 0.f;
        if (t < rem) {
            s = csr_src[start + base + t];
            w = __expf(lrelu(as2[s] + adv));
        }
        for (int jj = 0; jj < rem; ++jj) {
            int sj   = __shfl(s, jj, 64);
            float wj = __shfl(w, jj, 64);
            float hv = b2f(h2b[(size_t)sj * OUT_CH + tc]);
            den += wj;
            acc += wj * hv;
        }
    }
    if (!act) return;
    float o = acc / den + pf[P_B2 + t];
    size_t idx = (size_t)d * OUT_CH + t;
    if (*flagp) ((unsigned short*)outp)[idx] = f2b(o);
    else        ((float*)outp)[idx] = o;
}

extern "C" void kernel_launch(void* const* d_in, const int* in_sizes, int n_in,
                              void* d_out, int out_size, void* d_ws, size_t ws_size,
                              hipStream_t stream) {
    const void* x  = d_in[0];
    const int*  ei = (const int*)d_in[1];

    const int n_nodes = in_sizes[0] / IN_CH;     // 100000
    const int e_all   = in_sizes[1] / 2;         // 1700000
    const int* srcI = ei;
    const int* dstI = ei + e_all;

    float* ws = (float*)d_ws;
    const size_t n = (size_t)n_nodes;
    int* deg     = (int*)ws;
    int* offs    = deg + n;
    int* cursor  = offs + n;
    int* bsum    = cursor + n;
    int* bsumx   = bsum + 512;
    int* csr_src = bsumx + 512;
    float* A     = ws + 3 * n + 1024 + (size_t)e_all;
    float* as1   = A;
    float* ad1   = A + 8 * n;
    unsigned short* h1b = (unsigned short*)(A + 16 * n);
    float* as2   = A + 48 * n;
    float* ad2   = A + 49 * n;
    unsigned short* h2b = (unsigned short*)(A + 50 * n);
    int*   flagp = (int*)(A + 70 * n);
    float* pf    = A + 70 * n + 16;
    unsigned short* w1bf = (unsigned short*)(pf + P_TOT);   // 8192 bf16

    hipMemsetAsync(deg, 0, n * sizeof(int), stream);

    kA_fused<<<1024, 256, 0, stream>>>((const unsigned int*)x,
        d_in[2], d_in[3], d_in[4], d_in[5], d_in[6], d_in[7], d_in[8], d_in[9],
        dstI, deg, flagp, pf, w1bf, e_all, n_nodes);

    int nb = (n_nodes + 255) / 256;      // 391 <= 512
    kB1_scan<<<nb, 256, 0, stream>>>(deg, offs, bsum, n_nodes);
    kB2_scanb<<<1, 512, 0, stream>>>(bsum, bsumx, nb);
    kB3_fix<<<nb, 256, 0, stream>>>(offs, bsumx, cursor, n_nodes);

    kC_scatter<<<1024, 256, 0, stream>>>(srcI, dstI, cursor, csr_src, e_all, n_nodes);

    k1_mfma<<<(n_nodes + 63) / 64, 256, 0, stream>>>(x, w1bf, pf, flagp, h1b, as1, ad1, n_nodes);

    k34_fused<<<(n_nodes + 31) / 32, 256, 0, stream>>>(offs, deg, csr_src, as1, ad1, h1b, pf, h2b, as2, ad2, n_nodes);

    k6_fused2<<<(n_nodes + 3) / 4, 256, 0, stream>>>(offs, deg, csr_src, as2, ad2, h2b, pf, flagp, d_out, n_nodes);
}

// Round 12
// 464.205 us; speedup vs baseline: 1.0283x; 1.0283x over previous
//
#include <hip/hip_runtime.h>
#include <hip/hip_bf16.h>

#define IN_CH   128
#define HID     8
#define HEADS   8
#define C1      64      // HEADS*HID
#define OUT_CH  40
#define NEG     0.2f
#define NPART   8       // dst-space partitions, mapped to XCDs via blockIdx&7

typedef __attribute__((ext_vector_type(8))) short  short8;   // 8 bf16 (4 VGPRs)
typedef __attribute__((ext_vector_type(4))) float  f32x4;    // 4 fp32 acc

__device__ __forceinline__ float b2f(unsigned short u) {
    return __uint_as_float(((unsigned int)u) << 16);
}
__device__ __forceinline__ float blo(unsigned int p) { return __uint_as_float(p << 16); }
__device__ __forceinline__ float bhi(unsigned int p) { return __uint_as_float(p & 0xffff0000u); }
__device__ __forceinline__ unsigned short f2b(float f) {
    unsigned int u = __float_as_uint(f);
    unsigned int r = (u + 0x7fffu + ((u >> 16) & 1u)) >> 16;
    return (unsigned short)r;
}
__device__ __forceinline__ float lrelu(float v) { return v > 0.f ? v : NEG * v; }

// Param-block offsets (floats) inside canonical fp32 param buffer
#define P_W1    0
#define P_AS1   8192
#define P_AD1   8256
#define P_B1    8320
#define P_W2    8384
#define P_AS2   10944
#define P_AD2   10984
#define P_B2    11024
#define P_TOT   11064

// ---- kA_fused: dtype flag + param conversion (blocks 0..7) + partitioned
// histogram with int4 edge reads. 1024 blocks = 8 partitions x 128.
__global__ __launch_bounds__(256) void kA_fused(
        const unsigned int* __restrict__ x32,
        const void* W1, const void* as1p, const void* ad1p, const void* b1,
        const void* W2, const void* as2p, const void* ad2p, const void* b2,
        const int* __restrict__ dst, int* __restrict__ deg,
        int* __restrict__ flag, float* __restrict__ pf,
        unsigned short* __restrict__ w1bf,
        int e_all, int n_nodes) {
    int t = threadIdx.x;
    __shared__ int sflag;
    if (t < 64) {
        unsigned int lo = x32[t] & 0xffffu;
        int ex = (int)((lo >> 7) & 0xff);
        bool sane = (ex >= 112 && ex <= 143);
        unsigned long long m = __ballot(sane);
        if (t == 0) {
            int isbf = (__popcll(m) >= 32) ? 1 : 0;
            sflag = isbf;
            if (blockIdx.x == 0) *flag = isbf;
        }
    }
    __syncthreads();
    const int isbf = sflag;

    if (blockIdx.x < 8) {
        int g = blockIdx.x * 256 + t;     // 2048 threads over param arrays
#define CONV(dstoff, srcp, cnt)                                         \
        if (isbf) {                                                     \
            const unsigned short* sp = (const unsigned short*)(srcp);   \
            for (int i = g; i < (cnt); i += 2048) pf[(dstoff) + i] = b2f(sp[i]); \
        } else {                                                        \
            const float* sp = (const float*)(srcp);                     \
            for (int i = g; i < (cnt); i += 2048) pf[(dstoff) + i] = sp[i]; \
        }
        CONV(P_W1,  W1, 8192)
        CONV(P_AS1, as1p, 64)
        CONV(P_AD1, ad1p, 64)
        CONV(P_B1,  b1, 64)
        CONV(P_W2,  W2, 2560)
        CONV(P_AS2, as2p, 40)
        CONV(P_AD2, ad2p, 40)
        CONV(P_B2,  b2, 40)
#undef CONV
        if (isbf) {
            const unsigned short* sp = (const unsigned short*)W1;
            for (int i = g; i < 8192; i += 2048) w1bf[i] = sp[i];
        } else {
            const float* sp = (const float*)W1;
            for (int i = g; i < 8192; i += 2048) w1bf[i] = f2b(sp[i]);
        }
    }

    // partitioned histogram, int4 reads
    int part = blockIdx.x & (NPART - 1);
    int nm   = gridDim.x >> 3;
    int mblk = blockIdx.x >> 3;
    int lo = (int)((long long)part * n_nodes / NPART);
    int hi = (int)((long long)(part + 1) * n_nodes / NPART);
    const int4* dst4 = (const int4*)dst;
    int e4n = e_all >> 2;
    for (int i = mblk * 256 + t; i < e4n; i += nm * 256) {
        int4 d4 = dst4[i];
        if (d4.x >= lo && d4.x < hi) atomicAdd(&deg[d4.x], 1);
        if (d4.y >= lo && d4.y < hi) atomicAdd(&deg[d4.y], 1);
        if (d4.z >= lo && d4.z < hi) atomicAdd(&deg[d4.z], 1);
        if (d4.w >= lo && d4.w < hi) atomicAdd(&deg[d4.w], 1);
    }
    for (int e = (e4n << 2) + mblk * 256 + t; e < e_all; e += nm * 256) {
        int d = dst[e];
        if (d >= lo && d < hi) atomicAdd(&deg[d], 1);
    }
}

// ---- kB_alloc: single-kernel CSR range allocation ----------------------
// CSR ranges need only be disjoint, not node-ordered: LDS scan of 256 degs,
// one atomicAdd for the block base. Replaces the 3-kernel scan chain.
__global__ __launch_bounds__(256) void kB_alloc(
        const int* __restrict__ deg, int* __restrict__ offs,
        int* __restrict__ cursor, int* __restrict__ counter, int n) {
    __shared__ int sd[256];
    __shared__ int sbase;
    int t = threadIdx.x;
    int i = blockIdx.x * 256 + t;
    int v = (i < n) ? deg[i] : 0;
    sd[t] = v;
    __syncthreads();
    for (int off = 1; off < 256; off <<= 1) {
        int u = (t >= off) ? sd[t - off] : 0;
        __syncthreads();
        sd[t] += u;
        __syncthreads();
    }
    if (t == 255) sbase = atomicAdd(counter, sd[255]);
    __syncthreads();
    if (i < n) {
        int o = sbase + sd[t] - v;
        offs[i] = o;
        cursor[i] = o;
    }
}

__global__ __launch_bounds__(256) void kC_scatter(
        const int* __restrict__ src, const int* __restrict__ dst,
        int* __restrict__ cursor, int* __restrict__ csr_src,
        int e_all, int n_nodes) {
    int part = blockIdx.x & (NPART - 1);
    int nm   = gridDim.x >> 3;
    int mblk = blockIdx.x >> 3;
    int lo = (int)((long long)part * n_nodes / NPART);
    int hi = (int)((long long)(part + 1) * n_nodes / NPART);
    const int4* dst4 = (const int4*)dst;
    int e4n = e_all >> 2;
    for (int i = mblk * 256 + threadIdx.x; i < e4n; i += nm * 256) {
        int4 d4 = dst4[i];
        int eb = i << 2;
        if (d4.x >= lo && d4.x < hi) { int p = atomicAdd(&cursor[d4.x], 1); csr_src[p] = src[eb]; }
        if (d4.y >= lo && d4.y < hi) { int p = atomicAdd(&cursor[d4.y], 1); csr_src[p] = src[eb + 1]; }
        if (d4.z >= lo && d4.z < hi) { int p = atomicAdd(&cursor[d4.z], 1); csr_src[p] = src[eb + 2]; }
        if (d4.w >= lo && d4.w < hi) { int p = atomicAdd(&cursor[d4.w], 1); csr_src[p] = src[eb + 3]; }
    }
    for (int e = (e4n << 2) + mblk * 256 + threadIdx.x; e < e_all; e += nm * 256) {
        int d = dst[e];
        if (d >= lo && d < hi) { int p = atomicAdd(&cursor[d], 1); csr_src[p] = src[e]; }
    }
}

// ---- Layer 1 via MFMA: h1 = x @ W1^T, logits as1/ad1 --------------------
__global__ __launch_bounds__(256) void k1_mfma(
        const void* __restrict__ x, const unsigned short* __restrict__ w1bf,
        const float* __restrict__ pf, const int* __restrict__ flagp,
        unsigned short* __restrict__ h1b, float* __restrict__ as1, float* __restrict__ ad1,
        int n_nodes) {
    int tid = threadIdx.x;
    int wv = tid >> 6, L = tid & 63;
    int m = L & 15, q = L >> 4;
    int base = blockIdx.x * 64 + wv * 16;
    if (base >= n_nodes) return;
    const int isbf = *flagp;

    short8 bfr[4][4];
#pragma unroll
    for (int t = 0; t < 4; ++t)
#pragma unroll
        for (int kb = 0; kb < 4; ++kb)
            bfr[t][kb] = *(const short8*)(w1bf + (size_t)(t * 16 + m) * IN_CH + kb * 32 + q * 8);

    int row = base + m;
    if (row >= n_nodes) row = n_nodes - 1;   // tail clamp (loads only)
    short8 af[4];
    if (isbf) {
        const unsigned short* xr = (const unsigned short*)x + (size_t)row * IN_CH + q * 8;
#pragma unroll
        for (int kb = 0; kb < 4; ++kb) af[kb] = *(const short8*)(xr + kb * 32);
    } else {
        const float* xr = (const float*)x + (size_t)row * IN_CH + q * 8;
#pragma unroll
        for (int kb = 0; kb < 4; ++kb) {
            short8 a;
#pragma unroll
            for (int j = 0; j < 8; ++j) a[j] = (short)f2b(xr[kb * 32 + j]);
            af[kb] = a;
        }
    }

    f32x4 acc[4];
#pragma unroll
    for (int t = 0; t < 4; ++t) acc[t] = (f32x4){0.f, 0.f, 0.f, 0.f};
#pragma unroll
    for (int t = 0; t < 4; ++t)
#pragma unroll
        for (int kb = 0; kb < 4; ++kb)
            acc[t] = __builtin_amdgcn_mfma_f32_16x16x32_bf16(af[kb], bfr[t][kb], acc[t], 0, 0, 0);

#pragma unroll
    for (int t = 0; t < 4; ++t) {
#pragma unroll
        for (int r = 0; r < 4; ++r) {
            int node = base + q * 4 + r;
            bool ok = (node < n_nodes);
            float val = acc[t][r];
            int ch = t * 16 + m;
            if (ok) h1b[(size_t)node * C1 + ch] = f2b(val);
            float ps = val * pf[P_AS1 + ch];
            float pd = val * pf[P_AD1 + ch];
            ps += __shfl_xor(ps, 1, 64); ps += __shfl_xor(ps, 2, 64); ps += __shfl_xor(ps, 4, 64);
            pd += __shfl_xor(pd, 1, 64); pd += __shfl_xor(pd, 2, 64); pd += __shfl_xor(pd, 4, 64);
            if (ok && (L & 7) == 0) {
                int head = 2 * t + ((m >> 3) & 1);
                as1[(size_t)node * HEADS + head] = ps;
                ad1[(size_t)node * HEADS + head] = pd;
            }
        }
    }
}

// ---- Fused layer-1 aggregation: two-phase, lean (VGPR~20, no LDS) -------
__global__ __launch_bounds__(256) void k3_fused1(
        const int* __restrict__ offs, const int* __restrict__ deg,
        const int* __restrict__ csr_src,
        const float* __restrict__ as1, const float* __restrict__ ad1,
        const unsigned short* __restrict__ h1b, const float* __restrict__ pf,
        unsigned short* __restrict__ x2, int n_nodes) {
    int d = blockIdx.x * 4 + (threadIdx.x >> 6);
    if (d >= n_nodes) return;
    int t = threadIdx.x & 63;
    int head = t >> 3;                 // phase-2 role
    int j8 = t >> 3, h8 = t & 7;       // phase-1 role: edge j8, head h8
    float adv1 = ad1[(size_t)d * HEADS + h8];
    int start = offs[d];
    int dg = deg[d];
    float acc = 0.f, den = 0.f;
    int nfull = dg & ~7;
    int base = 0;
    for (; base < nfull; base += 8) {
        int s = csr_src[start + base + j8];
        float v = as1[(size_t)s * HEADS + h8] + adv1;
        float w = __expf(lrelu(v));
#pragma unroll
        for (int jj = 0; jj < 8; ++jj) {
            int sj   = __shfl(s, jj * 8, 64);
            float wj = __shfl(w, jj * 8 + head, 64);
            float hv = b2f(h1b[(size_t)sj * C1 + t]);
            den += wj;
            acc += wj * hv;
        }
    }
    int rem = dg - nfull;
    if (rem) {
        int s = 0; float w = 0.f;
        if (j8 < rem) {
            s = csr_src[start + base + j8];
            float v = as1[(size_t)s * HEADS + h8] + adv1;
            w = __expf(lrelu(v));
        }
        for (int jj = 0; jj < rem; ++jj) {
            int sj   = __shfl(s, jj * 8, 64);
            float wj = __shfl(w, jj * 8 + head, 64);
            float hv = b2f(h1b[(size_t)sj * C1 + t]);
            den += wj;
            acc += wj * hv;
        }
    }
    float o = acc / den + pf[P_B1 + t];
    o = o > 0.f ? o : (__expf(o) - 1.f);     // ELU
    x2[(size_t)d * C1 + t] = f2b(o);
}

// ---- Layer 2 GEMM (40 ch) via LDS-staged W2, 32 nodes/block -------------
__global__ __launch_bounds__(256) void k4_gemm2(
        const unsigned short* __restrict__ x2, const float* __restrict__ pf,
        unsigned short* __restrict__ h2b, float* __restrict__ as2, float* __restrict__ ad2,
        int n_nodes) {
    int tid = threadIdx.x;
    int w = tid >> 6, t = tid & 63;
    __shared__ float wTf[4096];          // W2 rotated, 16 groups x 64 slots x 4
    __shared__ float xsf[4 * C1];
    for (int e = tid; e < 2560; e += 256) {
        int row = e >> 6, k = e & 63;
        int g = k >> 2, j = k & 3;
        wTf[(g * 64 + ((row + g) & 63)) * 4 + j] = pf[P_W2 + e];
    }
    __syncthreads();
    const float4* wT4 = (const float4*)wTf;
    int base = blockIdx.x * 32 + w * 8;
    for (int i = 0; i < 8; ++i) {
        int n = base + i;
        bool ok = (n < n_nodes);
        if (ok && t < 32) {
            unsigned int p = ((const unsigned int*)x2)[(size_t)n * 32 + t];
            xsf[w * C1 + 2 * t]     = blo(p);
            xsf[w * C1 + 2 * t + 1] = bhi(p);
        }
        __syncthreads();
        if (ok) {
            float hs = 0.f, hd = 0.f;
            if (t < OUT_CH) {
                const float4* xv = (const float4*)(xsf + w * C1);
                float acc = 0.f;
#pragma unroll
                for (int g = 0; g < 16; ++g) {
                    float4 wv = wT4[g * 64 + ((t + g) & 63)];
                    float4 x4 = xv[g];
                    acc += x4.x * wv.x + x4.y * wv.y + x4.z * wv.z + x4.w * wv.w;
                }
                h2b[(size_t)n * OUT_CH + t] = f2b(acc);
                hs = acc * pf[P_AS2 + t];
                hd = acc * pf[P_AD2 + t];
            }
            for (int off = 1; off < 64; off <<= 1) {
                hs += __shfl_xor(hs, off, 64);
                hd += __shfl_xor(hd, off, 64);
            }
            if (t == 0) { as2[n] = hs; ad2[n] = hd; }
        }
        __syncthreads();
    }
}

// ---- Fused layer-2 aggregation: two-phase (16 weights in parallel) ------
__global__ __launch_bounds__(256) void k6_fused2(
        const int* __restrict__ offs, const int* __restrict__ deg,
        const int* __restrict__ csr_src,
        const float* __restrict__ as2, const float* __restrict__ ad2,
        const unsigned short* __restrict__ h2b, const float* __restrict__ pf,
        const int* __restrict__ flagp, void* __restrict__ outp, int n_nodes) {
    int d = blockIdx.x * 4 + (threadIdx.x >> 6);
    if (d >= n_nodes) return;
    int t = threadIdx.x & 63;
    float adv = ad2[d];
    int start = offs[d];
    int dg = deg[d];
    bool act = (t < OUT_CH);
    int tc = act ? t : 0;
    float acc = 0.f, den = 0.f;
    int nfull = dg & ~15;
    int base = 0;
    for (; base < nfull; base += 16) {
        int s = 0; float w = 0.f;
        if (t < 16) {
            s = csr_src[start + base + t];
            w = __expf(lrelu(as2[s] + adv));
        }
#pragma unroll
        for (int jj = 0; jj < 16; ++jj) {
            int sj   = __shfl(s, jj, 64);
            float wj = __shfl(w, jj, 64);
            float hv = b2f(h2b[(size_t)sj * OUT_CH + tc]);
            den += wj;
            acc += wj * hv;
        }
    }
    int rem = dg - nfull;
    if (rem) {
        int s = 0; float w = 0.f;
        if (t < rem) {
            s = csr_src[start + base + t];
            w = __expf(lrelu(as2[s] + adv));
        }
        for (int jj = 0; jj < rem; ++jj) {
            int sj   = __shfl(s, jj, 64);
            float wj = __shfl(w, jj, 64);
            float hv = b2f(h2b[(size_t)sj * OUT_CH + tc]);
            den += wj;
            acc += wj * hv;
        }
    }
    if (!act) return;
    float o = acc / den + pf[P_B2 + t];
    size_t idx = (size_t)d * OUT_CH + t;
    if (*flagp) ((unsigned short*)outp)[idx] = f2b(o);
    else        ((float*)outp)[idx] = o;
}

extern "C" void kernel_launch(void* const* d_in, const int* in_sizes, int n_in,
                              void* d_out, int out_size, void* d_ws, size_t ws_size,
                              hipStream_t stream) {
    const void* x  = d_in[0];
    const int*  ei = (const int*)d_in[1];

    const int n_nodes = in_sizes[0] / IN_CH;     // 100000
    const int e_all   = in_sizes[1] / 2;         // 1700000
    const int* srcI = ei;
    const int* dstI = ei + e_all;

    // Workspace (float units; n = n_nodes, E = e_all):
    //   [0, n)        deg (int, zeroed)
    //   [n]           counter (int, zeroed)
    //   [n+16, 2n+16) offs
    //   [2n+16,3n+16) cursor
    //   [3n+32, +E)   csr_src
    //   A = 3n+32+E:
    //   [A, A+8n)       as1
    //   [A+8n, A+16n)   ad1
    //   [A+16n, A+48n)  h1b bf16 (64/node)
    //   [A+48n, A+80n)  x2  bf16 (64/node)
    //   [A+80n, A+81n)  as2
    //   [A+81n, A+82n)  ad2
    //   [A+82n, A+102n) h2b bf16 (40/node)
    //   [A+102n]        flag
    //   [A+102n+16, ..) fp32 params (P_TOT) then w1bf (8192 bf16)
    float* ws = (float*)d_ws;
    const size_t n = (size_t)n_nodes;
    int* deg     = (int*)ws;
    int* counter = deg + n;
    int* offs    = (int*)(ws + n + 16);
    int* cursor  = (int*)(ws + 2 * n + 16);
    int* csr_src = (int*)(ws + 3 * n + 32);
    float* A     = ws + 3 * n + 32 + (size_t)e_all;
    float* as1   = A;
    float* ad1   = A + 8 * n;
    unsigned short* h1b = (unsigned short*)(A + 16 * n);
    unsigned short* x2  = (unsigned short*)(A + 48 * n);
    float* as2   = A + 80 * n;
    float* ad2   = A + 81 * n;
    unsigned short* h2b = (unsigned short*)(A + 82 * n);
    int*   flagp = (int*)(A + 102 * n);
    float* pf    = A + 102 * n + 16;
    unsigned short* w1bf = (unsigned short*)(pf + P_TOT);   // 8192 bf16

    hipMemsetAsync(ws, 0, (n + 16) * sizeof(int), stream);  // deg + counter

    kA_fused<<<1024, 256, 0, stream>>>((const unsigned int*)x,
        d_in[2], d_in[3], d_in[4], d_in[5], d_in[6], d_in[7], d_in[8], d_in[9],
        dstI, deg, flagp, pf, w1bf, e_all, n_nodes);

    int nb = (n_nodes + 255) / 256;
    kB_alloc<<<nb, 256, 0, stream>>>(deg, offs, cursor, counter, n_nodes);

    kC_scatter<<<1024, 256, 0, stream>>>(srcI, dstI, cursor, csr_src, e_all, n_nodes);

    k1_mfma<<<(n_nodes + 63) / 64, 256, 0, stream>>>(x, w1bf, pf, flagp, h1b, as1, ad1, n_nodes);

    k3_fused1<<<(n_nodes + 3) / 4, 256, 0, stream>>>(offs, deg, csr_src, as1, ad1, h1b, pf, x2, n_nodes);

    k4_gemm2<<<(n_nodes + 31) / 32, 256, 0, stream>>>(x2, pf, h2b, as2, ad2, n_nodes);

    k6_fused2<<<(n_nodes + 3) / 4, 256, 0, stream>>>(offs, deg, csr_src, as2, ad2, h2b, pf, flagp, d_out, n_nodes);
}